// Round 12
// baseline (237.203 us; speedup 1.0000x reference)
//
#include <hip/hip_runtime.h>

#define SLOPE 0.01f
#define EPSV  1e-5f
#define BB    64
#define NN    500
#define TT    50
#define E_N   16000
#define FF    43
#define PP    500
#define HH    128
#define XSTRIDE 48
#define PAD_E 40

typedef const float* fp;

__device__ __forceinline__ float lrelu(float x){ return x >= 0.f ? x : SLOPE * x; }
__device__ __forceinline__ float bnap(float x, fp bnp, int c, int C){
  float g  = bnp[c], b_ = bnp[C + c];
  float m  = bnp[2*C + c], v = bnp[3*C + c];
  float s = g * rsqrtf(v + EPSV);
  return x * s + (b_ - m * s);
}

// DPP-based 16-lane (one node = one DPP row) reductions.
#define DPP_I(x, c) __builtin_amdgcn_update_dpp(0, (x), (c), 0xF, 0xF, true)
__device__ __forceinline__ float rsum16(float x){
  x += __int_as_float(DPP_I(__float_as_int(x), 0xB1));   // quad_perm [1,0,3,2]
  x += __int_as_float(DPP_I(__float_as_int(x), 0x4E));   // quad_perm [2,3,0,1]
  x += __int_as_float(DPP_I(__float_as_int(x), 0x124));  // row_ror:4
  x += __int_as_float(DPP_I(__float_as_int(x), 0x128));  // row_ror:8
  return x;
}
__device__ __forceinline__ float rmax16(float x){
  x = fmaxf(x, __int_as_float(DPP_I(__float_as_int(x), 0xB1)));
  x = fmaxf(x, __int_as_float(DPP_I(__float_as_int(x), 0x4E)));
  x = fmaxf(x, __int_as_float(DPP_I(__float_as_int(x), 0x124)));
  x = fmaxf(x, __int_as_float(DPP_I(__float_as_int(x), 0x128)));
  return x;
}

// ============ tempo24 (exact r8 version — measured <=45us, VGPR 64) ====
__global__ __launch_bounds__(512) void k_tempo24(
    fp obs, fp sc1w, fp mc1w, fp sc2w, fp mc2w,
    fp sc1b, fp sbn1, fp sc2b, fp sbn2,
    fp mc1b, fp mbn1, fp mc2b, fp mbn2,
    const int* __restrict__ ei, const int* __restrict__ et,
    int* __restrict__ cntg, int* __restrict__ esp,
    float* __restrict__ xbuf)
{
  __shared__ float OL[4896];          // [w][612], 8 waves
  __shared__ float WSr[2880];         // raw sc2w [o][ci*48+tt]
  __shared__ float WMr[1800];         // raw mc2w [o][ci*30+tt]
  __shared__ float TBL[100];
  int tid  = threadIdx.x;
  int w    = tid >> 6, lane = tid & 63;
  int node = lane >> 4, seg = lane & 15;
  int gg   = __builtin_amdgcn_readfirstlane(blockIdx.x*8 + w);   // 0..7999
  int b    = gg / 125, ng = gg - b*125;
  int n0   = ng * 4;
  int wbase = w * 612;

  // ---- raw weight staging: coalesced global float4 -> consecutive LDS
  for (int i = tid; i < 720; i += 512) *(float4*)(WSr + i*4) = *(const float4*)(sc2w + i*4);
  for (int i = tid; i < 450; i += 512) *(float4*)(WMr + i*4) = *(const float4*)(mc2w + i*4);

  // ---- bn fold table
  if (tid < 20){
    float g = sbn2[tid], b_ = sbn2[20+tid], m = sbn2[40+tid], v = sbn2[60+tid];
    float s = g * rsqrtf(v + EPSV);
    TBL[tid] = s; TBL[43+tid] = sc2b[tid]*s + (b_ - m*s);
  } else if (tid < 40){
    int o = tid - 20;
    float g = mbn2[o], b_ = mbn2[20+o], m = mbn2[40+o], v = mbn2[60+o];
    float s = g * rsqrtf(v + EPSV);
    TBL[tid] = s; TBL[43+tid] = mc2b[o]*s + (b_ - m*s);
  } else if (tid < 43){
    TBL[tid] = 1.f; TBL[43+tid] = 0.f;
  } else if (tid < 46){
    int ci = tid - 43;
    float g = sbn1[ci], b_ = sbn1[3+ci], m = sbn1[6+ci], v = sbn1[9+ci];
    float s = g * rsqrtf(v + EPSV);
    TBL[86+ci] = s; TBL[89+ci] = sc1b[ci]*s + (b_ - m*s);
  } else if (tid < 49){
    int ci = tid - 46;
    float g = mbn1[ci], b_ = mbn1[3+ci], m = mbn1[6+ci], v = mbn1[9+ci];
    float s = g * rsqrtf(v + EPSV);
    TBL[92+ci] = s; TBL[95+ci] = mc1b[ci]*s + (b_ - m*s);
  }

  // ---- CSR duty (blocks 0..7): 2000 edges each, padded buckets
  if (blockIdx.x < 8){
    int base = blockIdx.x * 2000;
    #pragma unroll
    for (int k = 0; k < 4; k++){
      int el = k*512 + tid;
      if (el < 2000){
        int e = base + el;
        int s = ei[e], d = ei[E_N + e], r = et[e];
        int idx = d*4 + r;
        int pos = atomicAdd(&cntg[idx], 1);
        if (pos < PAD_E) esp[idx*PAD_E + pos] = s;
      }
    }
  }

  // ---- obs staging: 3 channels x 200 contiguous floats per wave (float4)
  for (int c = 0; c < 3; c++){
    if (lane < 50){
      const float4 v = *(const float4*)(obs + ((size_t)(b*3+c)*NN + n0)*TT + lane*4);
      int f = lane*4;
      int n = f/50, t = f - n*50;
      int a = wbase + c*204 + n*51 + t;
      OL[a] = v.x;
      if (++t == 50){ t = 0; n++; a = wbase + c*204 + n*51; } else a++;
      OL[a] = v.y;
      if (++t == 50){ t = 0; n++; a = wbase + c*204 + n*51; } else a++;
      OL[a] = v.z;
      if (++t == 50){ t = 0; n++; a = wbase + c*204 + n*51; } else a++;
      OL[a] = v.w;
    }
  }
  __syncthreads();

  int rb = wbase + node*51;
  int g  = b*NN + n0 + node;
  float* xr = xbuf + (size_t)g * XSTRIDE;
  float acc[20];

  // ================= S path: conv(3-tap) -> bn/lrelu -> conv2(48) =========
  {
    float mv[3][3];                       // [i][co], tt = seg*3 + i
    #pragma unroll
    for (int i = 0; i < 3; i++)
      #pragma unroll
      for (int co = 0; co < 3; co++) mv[i][co] = 0.f;
    int t0 = seg*3;                       // 0..45, window reads t0..t0+4 <= 49
    #pragma unroll
    for (int ci = 0; ci < 3; ci++){
      int ab = rb + ci*204 + t0;
      float v0 = OL[ab], v1 = OL[ab+1], v2 = OL[ab+2], v3 = OL[ab+3], v4 = OL[ab+4];
      #pragma unroll
      for (int co = 0; co < 3; co++){
        float w0 = sc1w[co*9+ci*3+0], w1 = sc1w[co*9+ci*3+1], w2 = sc1w[co*9+ci*3+2];
        mv[0][co] += v0*w0 + v1*w1 + v2*w2;
        mv[1][co] += v1*w0 + v2*w1 + v3*w2;
        mv[2][co] += v2*w0 + v3*w1 + v4*w2;
      }
    }
    #pragma unroll
    for (int o = 0; o < 20; o++) acc[o] = 0.f;
    #pragma unroll
    for (int i = 0; i < 3; i++){
      int tt = t0 + i;                    // 0..47
      #pragma unroll
      for (int co = 0; co < 3; co++){
        float z = lrelu(mv[i][co]*TBL[86+co] + TBL[89+co]);
        const float* wr = WSr + co*48 + tt;   // + o*144 per output
        #pragma unroll
        for (int o = 0; o < 20; o++)
          acc[o] += z * wr[o*144];
      }
    }
    #pragma unroll
    for (int o = 0; o < 20; o++) acc[o] = rsum16(acc[o]);
    #pragma unroll
    for (int o = 0; o < 20; o++)
      if (seg == (o & 15)) xr[o] = lrelu(acc[o]*TBL[o] + TBL[43+o]);
  }

  // ================= M path: conv(21-tap) -> bn/lrelu -> conv2(30) ========
  {
    float mv[2][3];                       // tt = seg*2 + i
    #pragma unroll
    for (int i = 0; i < 2; i++)
      #pragma unroll
      for (int co = 0; co < 3; co++) mv[i][co] = 0.f;
    int t0 = seg*2;                       // reads t0..t0+21 (seg15 overreads pad: masked)
    #pragma unroll
    for (int ci = 0; ci < 3; ci++){
      int ab = rb + ci*204 + t0;
      float vc = OL[ab];
      #pragma unroll
      for (int k = 0; k < 21; k++){
        float vn = OL[ab + k + 1];
        #pragma unroll
        for (int co = 0; co < 3; co++){
          float wk = mc1w[co*63 + ci*21 + k];
          mv[0][co] += vc*wk;
          mv[1][co] += vn*wk;
        }
        vc = vn;
      }
    }
    #pragma unroll
    for (int o = 0; o < 20; o++) acc[o] = 0.f;
    if (seg < 15){                        // tt = seg*2, seg*2+1 both < 30
      #pragma unroll
      for (int co = 0; co < 3; co++){
        float z0 = lrelu(mv[0][co]*TBL[92+co] + TBL[95+co]);
        float z1 = lrelu(mv[1][co]*TBL[92+co] + TBL[95+co]);
        const float* wr = WMr + co*30 + t0;   // + o*90 per output, 8B-aligned pairs
        #pragma unroll
        for (int o = 0; o < 20; o++){
          float2 q = *(const float2*)(wr + o*90);
          acc[o] += z0*q.x + z1*q.y;
        }
      }
    }
    #pragma unroll
    for (int o = 0; o < 20; o++) acc[o] = rsum16(acc[o]);
    #pragma unroll
    for (int o = 0; o < 20; o++)
      if (seg == (o & 15)) xr[20+o] = lrelu(acc[o]*TBL[20+o] + TBL[63+o]);
  }

  // ================= L path: max over t, lrelu ============================
  {
    float m0 = -3e38f, m1 = -3e38f, m2 = -3e38f;
    int l0 = seg*4;
    int ln = 50 - l0; if (ln > 4) ln = 4;  // segs 13..15: ln<=0 -> skip
    for (int j = 0; j < ln; j++){
      m0 = fmaxf(m0, OL[rb +       l0 + j]);
      m1 = fmaxf(m1, OL[rb + 204 + l0 + j]);
      m2 = fmaxf(m2, OL[rb + 408 + l0 + j]);
    }
    m0 = rmax16(m0); m1 = rmax16(m1); m2 = rmax16(m2);
    if (seg == 0) xr[40] = lrelu(m0);
    if (seg == 1) xr[41] = lrelu(m1);
    if (seg == 2) xr[42] = lrelu(m2);
  }
}

// ============ graph19: graph17 + interleaved 4-relation gather.
// Old: 16 serial bucket-chains per wave (cntg->e_s->xbuf pointer-chase, only
// 4 outstanding loads). New: all 4 counts/pointers loaded up front, one fused
// masked loop issues 8 index + 8 gather loads per iteration (16 in flight).
// inv_deg folded into the mask constant; tails masked via cndmask (index
// select to 0 keeps loads in-bounds; esp padded +4 for the j+1 read). ======
__global__ __launch_bounds__(1024) void k_graph19(
    const float* __restrict__ xbuf,
    fp gwroot, fp gwrel, fp gb, fp gbnp,
    const int* __restrict__ cntg, const int* __restrict__ esp,
    fp action, fp acw, fp acb,
    float* __restrict__ o_ws)
{
  __shared__ float xin[64][219];
  __shared__ float lred[16][64];
  int p = blockIdx.x;
  int l = ((p & 7) * 63) + (p >> 3);
  if (l >= 500) return;
  int tid = threadIdx.x;
  int w = tid >> 6, lane = tid & 63;
  int g0 = l * 64;

  for (int q = 0; q < 4; q++){
    int nl = (w << 2) + q;
    int g = __builtin_amdgcn_readfirstlane(g0 + nl);
    int b = g / NN;
    int n = g - b * NN;
    const float* xb = xbuf + (size_t)(b * NN) * XSTRIDE;
    float xv = (lane < FF) ? xbuf[(size_t)g*XSTRIDE + lane] : 0.f;

    int cA[4]; const int* ep_[4]; float inv_[4];
    int cmax = 0;
    #pragma unroll
    for (int r = 0; r < 4; r++){
      int idx = n*4 + r;
      int c = __builtin_amdgcn_readfirstlane(cntg[idx]);
      if (c > PAD_E) c = PAD_E;
      cA[r] = c;
      ep_[r] = esp + idx*PAD_E;
      inv_[r] = 1.f / fmaxf((float)c, 1.f);
      cmax = (c > cmax) ? c : cmax;
    }
    float aA[4] = {0.f,0.f,0.f,0.f};
    float aB[4] = {0.f,0.f,0.f,0.f};
    for (int j = 0; j < cmax; j += 2){
      #pragma unroll
      for (int r = 0; r < 4; r++){
        int s0 = (j     < cA[r]) ? ep_[r][j]   : 0;
        int s1 = (j + 1 < cA[r]) ? ep_[r][j+1] : 0;
        float m0 = (j     < cA[r]) ? inv_[r] : 0.f;
        float m1 = (j + 1 < cA[r]) ? inv_[r] : 0.f;
        float v0 = (lane < FF) ? xb[(size_t)s0*XSTRIDE + lane] : 0.f;
        float v1 = (lane < FF) ? xb[(size_t)s1*XSTRIDE + lane] : 0.f;
        aA[r] += m0 * v0;
        aB[r] += m1 * v1;
      }
    }
    if (lane < FF){
      xin[nl][lane]       = xv;
      xin[nl][ 43 + lane] = aA[0] + aB[0];
      xin[nl][ 86 + lane] = aA[1] + aB[1];
      xin[nl][129 + lane] = aA[2] + aB[2];
      xin[nl][172 + lane] = aA[3] + aB[3];
    }
  }
  __syncthreads();

  int c0 = __builtin_amdgcn_readfirstlane(w * 3);
  float acc[3];
  #pragma unroll
  for (int j = 0; j < 3; j++) acc[j] = (c0 + j < FF) ? gb[c0+j] : 0.f;
  for (int f = 0; f < 43; f++){
    float v = xin[lane][f];
    const float* wp = gwroot + f*43 + c0;
    #pragma unroll
    for (int j = 0; j < 3; j++) acc[j] += v * wp[j];
  }
  for (int f = 0; f < 172; f++){
    float v = xin[lane][43 + f];
    const float* wp = gwrel + f*43 + c0;
    #pragma unroll
    for (int j = 0; j < 3; j++) acc[j] += v * wp[j];
  }
  float lp = 0.f;
  #pragma unroll
  for (int j = 0; j < 3; j++){
    int c = c0 + j;
    if (c < FF){
      float gv = lrelu(bnap(acc[j], gbnp, c, FF));
      lp += gv * acw[1 + FF + c];
    }
  }
  if (w == 15){           // idle in channel space (c0=45): compute x-part
    int g = g0 + lane;
    int b = g / NN, n = g - b * NN;
    float xp = acb[0] + action[b*(PP+1) + 1 + n] * acw[0];
    #pragma unroll 2
    for (int c = 0; c < FF; c++) xp += xin[lane][c] * acw[1 + c];
    lp = xp;
  }
  lred[w][lane] = lp;
  __syncthreads();
  if (tid < 64){
    float t = 0.f;
    #pragma unroll
    for (int w2 = 0; w2 < 16; w2++) t += lred[w2][tid];
    int g2 = g0 + tid;
    int b = g2 / NN, n = g2 - b * NN;
    o_ws[b*(PP+1) + 1 + n] = t;
  }
}

// ============ fcall2 (unchanged) ============
__global__ __launch_bounds__(512) void k_fcall2(
    const float* __restrict__ o_ws,
    fp aw1, fp ab1, fp aw2, fp ab2, fp aw3, fp ab3,
    float* __restrict__ out)
{
  int b = blockIdx.x;
  int tid = threadIdx.x;
  __shared__ float os[PP+1];
  __shared__ float part[4][HH];
  __shared__ float h1[HH];
  __shared__ float h2[HH];
  __shared__ float red[512];

  if (tid <= PP) os[tid] = (tid == 0) ? 0.f : o_ws[b*(PP+1) + tid];
  __syncthreads();

  {
    int chunk = tid >> 7, h = tid & 127;
    int k0 = chunk * 125;
    int kn = (chunk == 3) ? 126 : 125;
    float acc = 0.f;
    for (int k = 0; k < kn; k++) acc += os[k0+k] * aw1[(k0+k)*HH + h];
    part[chunk][h] = acc;
  }
  __syncthreads();
  if (tid < HH)
    h1[tid] = fmaxf(ab1[tid] + part[0][tid] + part[1][tid] + part[2][tid] + part[3][tid], 0.f);
  __syncthreads();
  if (tid < HH){
    float acc = ab2[tid];
    #pragma unroll 4
    for (int k = 0; k < HH; k++) acc += h1[k] * aw2[k*HH + tid];
    h2[tid] = fmaxf(acc, 0.f);
  }
  __syncthreads();

  float val = -1e30f;
  if (tid <= PP){
    float acc = ab3[tid];
    #pragma unroll 4
    for (int k = 0; k < HH; k++) acc += h2[k] * aw3[k*(PP+1) + tid];
    val = acc;
  }
  red[tid] = val;
  __syncthreads();
  for (int s = 256; s > 0; s >>= 1){
    if (tid < s) red[tid] = fmaxf(red[tid], red[tid + s]);
    __syncthreads();
  }
  float mxv = red[0];
  __syncthreads();
  float e = (tid <= PP) ? expf(val - mxv) : 0.f;
  red[tid] = e;
  __syncthreads();
  for (int s = 256; s > 0; s >>= 1){
    if (tid < s) red[tid] += red[tid + s];
    __syncthreads();
  }
  float sum = red[0];
  if (tid <= PP) out[b*(PP+1) + tid] = e / sum;
}

extern "C" void kernel_launch(void* const* d_in, const int* in_sizes, int n_in,
                              void* d_out, int out_size, void* d_ws, size_t ws_size,
                              hipStream_t stream)
{
  fp obs    = (fp)d_in[0];
  fp action = (fp)d_in[1];
  const int* ei  = (const int*)d_in[2];
  const int* et  = (const int*)d_in[3];
  fp sc1w=(fp)d_in[5],  sc1b=(fp)d_in[6],  sbn1=(fp)d_in[7];
  fp sc2w=(fp)d_in[8],  sc2b=(fp)d_in[9],  sbn2=(fp)d_in[10];
  fp mc1w=(fp)d_in[11], mc1b=(fp)d_in[12], mbn1=(fp)d_in[13];
  fp mc2w=(fp)d_in[14], mc2b=(fp)d_in[15], mbn2=(fp)d_in[16];
  fp gwroot=(fp)d_in[17], gwrel=(fp)d_in[18], gb=(fp)d_in[19], gbnp=(fp)d_in[20];
  fp acw=(fp)d_in[21], acb=(fp)d_in[22];
  fp aw1=(fp)d_in[23], ab1=(fp)d_in[24];
  fp aw2=(fp)d_in[25], ab2=(fp)d_in[26];
  fp aw3=(fp)d_in[27], ab3=(fp)d_in[28];

  float* xbuf   = (float*)d_ws;              // 1,536,000
  float* o_ws   = xbuf + 1536000;            // 32,064
  int*   cntg   = (int*)(o_ws + 32064);      // 2,000
  int*   esp    = cntg + 2000;               // 80,004 (+4 pad: masked j+1 read)

  float* out = (float*)d_out;

  hipMemsetAsync(cntg, 0, 2000*sizeof(int), stream);
  hipLaunchKernelGGL(k_tempo24, dim3(1000), dim3(512), 0, stream,
    obs, sc1w, mc1w, sc2w, mc2w,
    sc1b, sbn1, sc2b, sbn2, mc1b, mbn1, mc2b, mbn2,
    ei, et, cntg, esp, xbuf);
  hipLaunchKernelGGL(k_graph19, dim3(504), dim3(1024), 0, stream,
    xbuf, gwroot, gwrel, gb, gbnp, cntg, esp, action, acw, acb, o_ws);
  hipLaunchKernelGGL(k_fcall2, dim3(BB), dim3(512), 0, stream,
    o_ws, aw1, ab1, aw2, ab2, aw3, ab3, out);
}

// Round 13
// 216.824 us; speedup vs baseline: 1.0940x; 1.0940x over previous
//
#include <hip/hip_runtime.h>

#define SLOPE 0.01f
#define EPSV  1e-5f
#define BB    64
#define NN    500
#define TT    50
#define E_N   16000
#define FF    43
#define PP    500
#define HH    128
#define XSTRIDE 48
#define PAD_E 40

typedef const float* fp;

__device__ __forceinline__ float lrelu(float x){ return x >= 0.f ? x : SLOPE * x; }
__device__ __forceinline__ float bnap(float x, fp bnp, int c, int C){
  float g  = bnp[c], b_ = bnp[C + c];
  float m  = bnp[2*C + c], v = bnp[3*C + c];
  float s = g * rsqrtf(v + EPSV);
  return x * s + (b_ - m * s);
}

// DPP-based 16-lane (one node = one DPP row) reductions.
#define DPP_I(x, c) __builtin_amdgcn_update_dpp(0, (x), (c), 0xF, 0xF, true)
__device__ __forceinline__ float rsum16(float x){
  x += __int_as_float(DPP_I(__float_as_int(x), 0xB1));   // quad_perm [1,0,3,2]
  x += __int_as_float(DPP_I(__float_as_int(x), 0x4E));   // quad_perm [2,3,0,1]
  x += __int_as_float(DPP_I(__float_as_int(x), 0x124));  // row_ror:4
  x += __int_as_float(DPP_I(__float_as_int(x), 0x128));  // row_ror:8
  return x;
}
__device__ __forceinline__ float rmax16(float x){
  x = fmaxf(x, __int_as_float(DPP_I(__float_as_int(x), 0xB1)));
  x = fmaxf(x, __int_as_float(DPP_I(__float_as_int(x), 0x4E)));
  x = fmaxf(x, __int_as_float(DPP_I(__float_as_int(x), 0x124)));
  x = fmaxf(x, __int_as_float(DPP_I(__float_as_int(x), 0x128)));
  return x;
}

// ============ tempo24 (exact r8 version — measured <=45us) ====
__global__ __launch_bounds__(512) void k_tempo24(
    fp obs, fp sc1w, fp mc1w, fp sc2w, fp mc2w,
    fp sc1b, fp sbn1, fp sc2b, fp sbn2,
    fp mc1b, fp mbn1, fp mc2b, fp mbn2,
    const int* __restrict__ ei, const int* __restrict__ et,
    int* __restrict__ cntg, int* __restrict__ esp,
    float* __restrict__ xbuf)
{
  __shared__ float OL[4896];          // [w][612], 8 waves
  __shared__ float WSr[2880];         // raw sc2w [o][ci*48+tt]
  __shared__ float WMr[1800];         // raw mc2w [o][ci*30+tt]
  __shared__ float TBL[100];
  int tid  = threadIdx.x;
  int w    = tid >> 6, lane = tid & 63;
  int node = lane >> 4, seg = lane & 15;
  int gg   = __builtin_amdgcn_readfirstlane(blockIdx.x*8 + w);   // 0..7999
  int b    = gg / 125, ng = gg - b*125;
  int n0   = ng * 4;
  int wbase = w * 612;

  // ---- raw weight staging: coalesced global float4 -> consecutive LDS
  for (int i = tid; i < 720; i += 512) *(float4*)(WSr + i*4) = *(const float4*)(sc2w + i*4);
  for (int i = tid; i < 450; i += 512) *(float4*)(WMr + i*4) = *(const float4*)(mc2w + i*4);

  // ---- bn fold table
  if (tid < 20){
    float g = sbn2[tid], b_ = sbn2[20+tid], m = sbn2[40+tid], v = sbn2[60+tid];
    float s = g * rsqrtf(v + EPSV);
    TBL[tid] = s; TBL[43+tid] = sc2b[tid]*s + (b_ - m*s);
  } else if (tid < 40){
    int o = tid - 20;
    float g = mbn2[o], b_ = mbn2[20+o], m = mbn2[40+o], v = mbn2[60+o];
    float s = g * rsqrtf(v + EPSV);
    TBL[tid] = s; TBL[43+tid] = mc2b[o]*s + (b_ - m*s);
  } else if (tid < 43){
    TBL[tid] = 1.f; TBL[43+tid] = 0.f;
  } else if (tid < 46){
    int ci = tid - 43;
    float g = sbn1[ci], b_ = sbn1[3+ci], m = sbn1[6+ci], v = sbn1[9+ci];
    float s = g * rsqrtf(v + EPSV);
    TBL[86+ci] = s; TBL[89+ci] = sc1b[ci]*s + (b_ - m*s);
  } else if (tid < 49){
    int ci = tid - 46;
    float g = mbn1[ci], b_ = mbn1[3+ci], m = mbn1[6+ci], v = mbn1[9+ci];
    float s = g * rsqrtf(v + EPSV);
    TBL[92+ci] = s; TBL[95+ci] = mc1b[ci]*s + (b_ - m*s);
  }

  // ---- CSR duty (blocks 0..7): 2000 edges each, padded buckets
  if (blockIdx.x < 8){
    int base = blockIdx.x * 2000;
    #pragma unroll
    for (int k = 0; k < 4; k++){
      int el = k*512 + tid;
      if (el < 2000){
        int e = base + el;
        int s = ei[e], d = ei[E_N + e], r = et[e];
        int idx = d*4 + r;
        int pos = atomicAdd(&cntg[idx], 1);
        if (pos < PAD_E) esp[idx*PAD_E + pos] = s;
      }
    }
  }

  // ---- obs staging: 3 channels x 200 contiguous floats per wave (float4)
  for (int c = 0; c < 3; c++){
    if (lane < 50){
      const float4 v = *(const float4*)(obs + ((size_t)(b*3+c)*NN + n0)*TT + lane*4);
      int f = lane*4;
      int n = f/50, t = f - n*50;
      int a = wbase + c*204 + n*51 + t;
      OL[a] = v.x;
      if (++t == 50){ t = 0; n++; a = wbase + c*204 + n*51; } else a++;
      OL[a] = v.y;
      if (++t == 50){ t = 0; n++; a = wbase + c*204 + n*51; } else a++;
      OL[a] = v.z;
      if (++t == 50){ t = 0; n++; a = wbase + c*204 + n*51; } else a++;
      OL[a] = v.w;
    }
  }
  __syncthreads();

  int rb = wbase + node*51;
  int g  = b*NN + n0 + node;
  float* xr = xbuf + (size_t)g * XSTRIDE;
  float acc[20];

  // ================= S path =========
  {
    float mv[3][3];
    #pragma unroll
    for (int i = 0; i < 3; i++)
      #pragma unroll
      for (int co = 0; co < 3; co++) mv[i][co] = 0.f;
    int t0 = seg*3;
    #pragma unroll
    for (int ci = 0; ci < 3; ci++){
      int ab = rb + ci*204 + t0;
      float v0 = OL[ab], v1 = OL[ab+1], v2 = OL[ab+2], v3 = OL[ab+3], v4 = OL[ab+4];
      #pragma unroll
      for (int co = 0; co < 3; co++){
        float w0 = sc1w[co*9+ci*3+0], w1 = sc1w[co*9+ci*3+1], w2 = sc1w[co*9+ci*3+2];
        mv[0][co] += v0*w0 + v1*w1 + v2*w2;
        mv[1][co] += v1*w0 + v2*w1 + v3*w2;
        mv[2][co] += v2*w0 + v3*w1 + v4*w2;
      }
    }
    #pragma unroll
    for (int o = 0; o < 20; o++) acc[o] = 0.f;
    #pragma unroll
    for (int i = 0; i < 3; i++){
      int tt = t0 + i;
      #pragma unroll
      for (int co = 0; co < 3; co++){
        float z = lrelu(mv[i][co]*TBL[86+co] + TBL[89+co]);
        const float* wr = WSr + co*48 + tt;
        #pragma unroll
        for (int o = 0; o < 20; o++)
          acc[o] += z * wr[o*144];
      }
    }
    #pragma unroll
    for (int o = 0; o < 20; o++) acc[o] = rsum16(acc[o]);
    #pragma unroll
    for (int o = 0; o < 20; o++)
      if (seg == (o & 15)) xr[o] = lrelu(acc[o]*TBL[o] + TBL[43+o]);
  }

  // ================= M path ========
  {
    float mv[2][3];
    #pragma unroll
    for (int i = 0; i < 2; i++)
      #pragma unroll
      for (int co = 0; co < 3; co++) mv[i][co] = 0.f;
    int t0 = seg*2;
    #pragma unroll
    for (int ci = 0; ci < 3; ci++){
      int ab = rb + ci*204 + t0;
      float vc = OL[ab];
      #pragma unroll
      for (int k = 0; k < 21; k++){
        float vn = OL[ab + k + 1];
        #pragma unroll
        for (int co = 0; co < 3; co++){
          float wk = mc1w[co*63 + ci*21 + k];
          mv[0][co] += vc*wk;
          mv[1][co] += vn*wk;
        }
        vc = vn;
      }
    }
    #pragma unroll
    for (int o = 0; o < 20; o++) acc[o] = 0.f;
    if (seg < 15){
      #pragma unroll
      for (int co = 0; co < 3; co++){
        float z0 = lrelu(mv[0][co]*TBL[92+co] + TBL[95+co]);
        float z1 = lrelu(mv[1][co]*TBL[92+co] + TBL[95+co]);
        const float* wr = WMr + co*30 + t0;
        #pragma unroll
        for (int o = 0; o < 20; o++){
          float2 q = *(const float2*)(wr + o*90);
          acc[o] += z0*q.x + z1*q.y;
        }
      }
    }
    #pragma unroll
    for (int o = 0; o < 20; o++) acc[o] = rsum16(acc[o]);
    #pragma unroll
    for (int o = 0; o < 20; o++)
      if (seg == (o & 15)) xr[20+o] = lrelu(acc[o]*TBL[20+o] + TBL[63+o]);
  }

  // ================= L path ============================
  {
    float m0 = -3e38f, m1 = -3e38f, m2 = -3e38f;
    int l0 = seg*4;
    int ln = 50 - l0; if (ln > 4) ln = 4;
    for (int j = 0; j < ln; j++){
      m0 = fmaxf(m0, OL[rb +       l0 + j]);
      m1 = fmaxf(m1, OL[rb + 204 + l0 + j]);
      m2 = fmaxf(m2, OL[rb + 408 + l0 + j]);
    }
    m0 = rmax16(m0); m1 = rmax16(m1); m2 = rmax16(m2);
    if (seg == 0) xr[40] = lrelu(m0);
    if (seg == 1) xr[41] = lrelu(m1);
    if (seg == 2) xr[42] = lrelu(m2);
  }
}

// ============ graph20: NODE-major blocking. One block per node n, all 64
// batches as rows. Bucket indices are batch-independent -> each wave s_loads
// an index ONCE and issues 4 independent gathers (one per owned batch);
// j-unroll x4 puts 16 independent gathers in flight per uniform-index round.
// Exact per-bucket counts (no masked-load waste — r12 lesson). Matvec phase
// isomorphic to graph17 with rows=batches. ======
__global__ __launch_bounds__(1024) void k_graph20(
    const float* __restrict__ xbuf,
    fp gwroot, fp gwrel, fp gb, fp gbnp,
    const int* __restrict__ cntg, const int* __restrict__ esp,
    fp action, fp acw, fp acb,
    float* __restrict__ o_ws)
{
  __shared__ float xin[64][219];       // rows = batches
  __shared__ float lred[16][64];
  int n = blockIdx.x;                  // node 0..499
  int tid = threadIdx.x;
  int w = tid >> 6, lane = tid & 63;
  int b0 = w * 4;                      // this wave's 4 batches

  const float* xb0 = xbuf + (size_t)((b0+0)*NN) * XSTRIDE;
  const float* xb1 = xbuf + (size_t)((b0+1)*NN) * XSTRIDE;
  const float* xb2 = xbuf + (size_t)((b0+2)*NN) * XSTRIDE;
  const float* xb3 = xbuf + (size_t)((b0+3)*NN) * XSTRIDE;

  // own-node features for the 4 batches
  if (lane < FF){
    xin[b0+0][lane] = xb0[(size_t)n*XSTRIDE + lane];
    xin[b0+1][lane] = xb1[(size_t)n*XSTRIDE + lane];
    xin[b0+2][lane] = xb2[(size_t)n*XSTRIDE + lane];
    xin[b0+3][lane] = xb3[(size_t)n*XSTRIDE + lane];
  }

  #pragma unroll
  for (int r = 0; r < 4; r++){
    int idx = n*4 + r;
    int c = __builtin_amdgcn_readfirstlane(cntg[idx]);
    if (c > PAD_E) c = PAD_E;
    const int* ep = esp + idx*PAD_E;
    float a0 = 0.f, a1 = 0.f, a2 = 0.f, a3 = 0.f;
    int i = 0;
    for (; i + 4 <= c; i += 4){
      int s0 = ep[i], s1 = ep[i+1], s2 = ep[i+2], s3 = ep[i+3];
      size_t o0 = (size_t)s0*XSTRIDE + lane, o1 = (size_t)s1*XSTRIDE + lane;
      size_t o2 = (size_t)s2*XSTRIDE + lane, o3 = (size_t)s3*XSTRIDE + lane;
      if (lane < FF){
        a0 += xb0[o0] + xb0[o1] + xb0[o2] + xb0[o3];
        a1 += xb1[o0] + xb1[o1] + xb1[o2] + xb1[o3];
        a2 += xb2[o0] + xb2[o1] + xb2[o2] + xb2[o3];
        a3 += xb3[o0] + xb3[o1] + xb3[o2] + xb3[o3];
      }
    }
    for (; i < c; i++){
      int s = ep[i];
      size_t o = (size_t)s*XSTRIDE + lane;
      if (lane < FF){
        a0 += xb0[o]; a1 += xb1[o]; a2 += xb2[o]; a3 += xb3[o];
      }
    }
    float inv = 1.f / fmaxf((float)c, 1.f);
    if (lane < FF){
      xin[b0+0][43 + 43*r + lane] = a0 * inv;
      xin[b0+1][43 + 43*r + lane] = a1 * inv;
      xin[b0+2][43 + 43*r + lane] = a2 * inv;
      xin[b0+3][43 + 43*r + lane] = a3 * inv;
    }
  }
  __syncthreads();

  // ---- transform + fused logits: lane = batch, channels split over waves
  int c0 = __builtin_amdgcn_readfirstlane(w * 3);
  float acc[3];
  #pragma unroll
  for (int j = 0; j < 3; j++) acc[j] = (c0 + j < FF) ? gb[c0+j] : 0.f;
  for (int f = 0; f < 43; f++){
    float v = xin[lane][f];
    const float* wp = gwroot + f*43 + c0;
    #pragma unroll
    for (int j = 0; j < 3; j++) acc[j] += v * wp[j];
  }
  for (int f = 0; f < 172; f++){
    float v = xin[lane][43 + f];
    const float* wp = gwrel + f*43 + c0;
    #pragma unroll
    for (int j = 0; j < 3; j++) acc[j] += v * wp[j];
  }
  float lp = 0.f;
  #pragma unroll
  for (int j = 0; j < 3; j++){
    int c = c0 + j;
    if (c < FF){
      float gv = lrelu(bnap(acc[j], gbnp, c, FF));
      lp += gv * acw[1 + FF + c];
    }
  }
  if (w == 15){          // idle in channel space: x/action part (lane = batch)
    float xp = acb[0] + action[lane*(PP+1) + 1 + n] * acw[0];
    #pragma unroll 2
    for (int c = 0; c < FF; c++) xp += xin[lane][c] * acw[1 + c];
    lp = xp;
  }
  lred[w][lane] = lp;
  __syncthreads();
  if (tid < 64){
    float t = 0.f;
    #pragma unroll
    for (int w2 = 0; w2 < 16; w2++) t += lred[w2][tid];
    o_ws[tid*(PP+1) + 1 + n] = t;
  }
}

// ============ fcall2 (unchanged) ============
__global__ __launch_bounds__(512) void k_fcall2(
    const float* __restrict__ o_ws,
    fp aw1, fp ab1, fp aw2, fp ab2, fp aw3, fp ab3,
    float* __restrict__ out)
{
  int b = blockIdx.x;
  int tid = threadIdx.x;
  __shared__ float os[PP+1];
  __shared__ float part[4][HH];
  __shared__ float h1[HH];
  __shared__ float h2[HH];
  __shared__ float red[512];

  if (tid <= PP) os[tid] = (tid == 0) ? 0.f : o_ws[b*(PP+1) + tid];
  __syncthreads();

  {
    int chunk = tid >> 7, h = tid & 127;
    int k0 = chunk * 125;
    int kn = (chunk == 3) ? 126 : 125;
    float acc = 0.f;
    for (int k = 0; k < kn; k++) acc += os[k0+k] * aw1[(k0+k)*HH + h];
    part[chunk][h] = acc;
  }
  __syncthreads();
  if (tid < HH)
    h1[tid] = fmaxf(ab1[tid] + part[0][tid] + part[1][tid] + part[2][tid] + part[3][tid], 0.f);
  __syncthreads();
  if (tid < HH){
    float acc = ab2[tid];
    #pragma unroll 4
    for (int k = 0; k < HH; k++) acc += h1[k] * aw2[k*HH + tid];
    h2[tid] = fmaxf(acc, 0.f);
  }
  __syncthreads();

  float val = -1e30f;
  if (tid <= PP){
    float acc = ab3[tid];
    #pragma unroll 4
    for (int k = 0; k < HH; k++) acc += h2[k] * aw3[k*(PP+1) + tid];
    val = acc;
  }
  red[tid] = val;
  __syncthreads();
  for (int s = 256; s > 0; s >>= 1){
    if (tid < s) red[tid] = fmaxf(red[tid], red[tid + s]);
    __syncthreads();
  }
  float mxv = red[0];
  __syncthreads();
  float e = (tid <= PP) ? expf(val - mxv) : 0.f;
  red[tid] = e;
  __syncthreads();
  for (int s = 256; s > 0; s >>= 1){
    if (tid < s) red[tid] += red[tid + s];
    __syncthreads();
  }
  float sum = red[0];
  if (tid <= PP) out[b*(PP+1) + tid] = e / sum;
}

extern "C" void kernel_launch(void* const* d_in, const int* in_sizes, int n_in,
                              void* d_out, int out_size, void* d_ws, size_t ws_size,
                              hipStream_t stream)
{
  fp obs    = (fp)d_in[0];
  fp action = (fp)d_in[1];
  const int* ei  = (const int*)d_in[2];
  const int* et  = (const int*)d_in[3];
  fp sc1w=(fp)d_in[5],  sc1b=(fp)d_in[6],  sbn1=(fp)d_in[7];
  fp sc2w=(fp)d_in[8],  sc2b=(fp)d_in[9],  sbn2=(fp)d_in[10];
  fp mc1w=(fp)d_in[11], mc1b=(fp)d_in[12], mbn1=(fp)d_in[13];
  fp mc2w=(fp)d_in[14], mc2b=(fp)d_in[15], mbn2=(fp)d_in[16];
  fp gwroot=(fp)d_in[17], gwrel=(fp)d_in[18], gb=(fp)d_in[19], gbnp=(fp)d_in[20];
  fp acw=(fp)d_in[21], acb=(fp)d_in[22];
  fp aw1=(fp)d_in[23], ab1=(fp)d_in[24];
  fp aw2=(fp)d_in[25], ab2=(fp)d_in[26];
  fp aw3=(fp)d_in[27], ab3=(fp)d_in[28];

  float* xbuf   = (float*)d_ws;              // 1,536,000
  float* o_ws   = xbuf + 1536000;            // 32,064
  int*   cntg   = (int*)(o_ws + 32064);      // 2,000
  int*   esp    = cntg + 2000;               // 80,000

  float* out = (float*)d_out;

  hipMemsetAsync(cntg, 0, 2000*sizeof(int), stream);
  hipLaunchKernelGGL(k_tempo24, dim3(1000), dim3(512), 0, stream,
    obs, sc1w, mc1w, sc2w, mc2w,
    sc1b, sbn1, sc2b, sbn2, mc1b, mbn1, mc2b, mbn2,
    ei, et, cntg, esp, xbuf);
  hipLaunchKernelGGL(k_graph20, dim3(500), dim3(1024), 0, stream,
    xbuf, gwroot, gwrel, gb, gbnp, cntg, esp, action, acw, acb, o_ws);
  hipLaunchKernelGGL(k_fcall2, dim3(BB), dim3(512), 0, stream,
    o_ws, aw1, ab1, aw2, ab2, aw3, ab3, out);
}

// Round 14
// 215.603 us; speedup vs baseline: 1.1002x; 1.0057x over previous
//
#include <hip/hip_runtime.h>

#define SLOPE 0.01f
#define EPSV  1e-5f
#define BB    64
#define NN    500
#define TT    50
#define E_N   16000
#define FF    43
#define PP    500
#define HH    128
#define XSTRIDE 48
#define PAD_E 40

typedef const float* fp;

__device__ __forceinline__ float lrelu(float x){ return x >= 0.f ? x : SLOPE * x; }
__device__ __forceinline__ float bnap(float x, fp bnp, int c, int C){
  float g  = bnp[c], b_ = bnp[C + c];
  float m  = bnp[2*C + c], v = bnp[3*C + c];
  float s = g * rsqrtf(v + EPSV);
  return x * s + (b_ - m * s);
}

// DPP-based 16-lane (one node = one DPP row) reductions.
#define DPP_I(x, c) __builtin_amdgcn_update_dpp(0, (x), (c), 0xF, 0xF, true)
__device__ __forceinline__ float rsum16(float x){
  x += __int_as_float(DPP_I(__float_as_int(x), 0xB1));   // quad_perm [1,0,3,2]
  x += __int_as_float(DPP_I(__float_as_int(x), 0x4E));   // quad_perm [2,3,0,1]
  x += __int_as_float(DPP_I(__float_as_int(x), 0x124));  // row_ror:4
  x += __int_as_float(DPP_I(__float_as_int(x), 0x128));  // row_ror:8
  return x;
}
__device__ __forceinline__ float rmax16(float x){
  x = fmaxf(x, __int_as_float(DPP_I(__float_as_int(x), 0xB1)));
  x = fmaxf(x, __int_as_float(DPP_I(__float_as_int(x), 0x4E)));
  x = fmaxf(x, __int_as_float(DPP_I(__float_as_int(x), 0x124)));
  x = fmaxf(x, __int_as_float(DPP_I(__float_as_int(x), 0x128)));
  return x;
}

// ============ tempo26: tempo24 minus CSR duty (CSR now built inside graph).
__global__ __launch_bounds__(512) void k_tempo26(
    fp obs, fp sc1w, fp mc1w, fp sc2w, fp mc2w,
    fp sc1b, fp sbn1, fp sc2b, fp sbn2,
    fp mc1b, fp mbn1, fp mc2b, fp mbn2,
    float* __restrict__ xbuf)
{
  __shared__ float OL[4896];          // [w][612], 8 waves
  __shared__ float WSr[2880];         // raw sc2w [o][ci*48+tt]
  __shared__ float WMr[1800];         // raw mc2w [o][ci*30+tt]
  __shared__ float TBL[100];
  int tid  = threadIdx.x;
  int w    = tid >> 6, lane = tid & 63;
  int node = lane >> 4, seg = lane & 15;
  int gg   = __builtin_amdgcn_readfirstlane(blockIdx.x*8 + w);   // 0..7999
  int b    = gg / 125, ng = gg - b*125;
  int n0   = ng * 4;
  int wbase = w * 612;

  // ---- raw weight staging: coalesced global float4 -> consecutive LDS
  for (int i = tid; i < 720; i += 512) *(float4*)(WSr + i*4) = *(const float4*)(sc2w + i*4);
  for (int i = tid; i < 450; i += 512) *(float4*)(WMr + i*4) = *(const float4*)(mc2w + i*4);

  // ---- bn fold table
  if (tid < 20){
    float g = sbn2[tid], b_ = sbn2[20+tid], m = sbn2[40+tid], v = sbn2[60+tid];
    float s = g * rsqrtf(v + EPSV);
    TBL[tid] = s; TBL[43+tid] = sc2b[tid]*s + (b_ - m*s);
  } else if (tid < 40){
    int o = tid - 20;
    float g = mbn2[o], b_ = mbn2[20+o], m = mbn2[40+o], v = mbn2[60+o];
    float s = g * rsqrtf(v + EPSV);
    TBL[tid] = s; TBL[43+tid] = mc2b[o]*s + (b_ - m*s);
  } else if (tid < 43){
    TBL[tid] = 1.f; TBL[43+tid] = 0.f;
  } else if (tid < 46){
    int ci = tid - 43;
    float g = sbn1[ci], b_ = sbn1[3+ci], m = sbn1[6+ci], v = sbn1[9+ci];
    float s = g * rsqrtf(v + EPSV);
    TBL[86+ci] = s; TBL[89+ci] = sc1b[ci]*s + (b_ - m*s);
  } else if (tid < 49){
    int ci = tid - 46;
    float g = mbn1[ci], b_ = mbn1[3+ci], m = mbn1[6+ci], v = mbn1[9+ci];
    float s = g * rsqrtf(v + EPSV);
    TBL[92+ci] = s; TBL[95+ci] = mc1b[ci]*s + (b_ - m*s);
  }

  // ---- obs staging: 3 channels x 200 contiguous floats per wave (float4)
  for (int c = 0; c < 3; c++){
    if (lane < 50){
      const float4 v = *(const float4*)(obs + ((size_t)(b*3+c)*NN + n0)*TT + lane*4);
      int f = lane*4;
      int n = f/50, t = f - n*50;
      int a = wbase + c*204 + n*51 + t;
      OL[a] = v.x;
      if (++t == 50){ t = 0; n++; a = wbase + c*204 + n*51; } else a++;
      OL[a] = v.y;
      if (++t == 50){ t = 0; n++; a = wbase + c*204 + n*51; } else a++;
      OL[a] = v.z;
      if (++t == 50){ t = 0; n++; a = wbase + c*204 + n*51; } else a++;
      OL[a] = v.w;
    }
  }
  __syncthreads();

  int rb = wbase + node*51;
  int g  = b*NN + n0 + node;
  float* xr = xbuf + (size_t)g * XSTRIDE;
  float acc[20];

  // ================= S path =========
  {
    float mv[3][3];
    #pragma unroll
    for (int i = 0; i < 3; i++)
      #pragma unroll
      for (int co = 0; co < 3; co++) mv[i][co] = 0.f;
    int t0 = seg*3;
    #pragma unroll
    for (int ci = 0; ci < 3; ci++){
      int ab = rb + ci*204 + t0;
      float v0 = OL[ab], v1 = OL[ab+1], v2 = OL[ab+2], v3 = OL[ab+3], v4 = OL[ab+4];
      #pragma unroll
      for (int co = 0; co < 3; co++){
        float w0 = sc1w[co*9+ci*3+0], w1 = sc1w[co*9+ci*3+1], w2 = sc1w[co*9+ci*3+2];
        mv[0][co] += v0*w0 + v1*w1 + v2*w2;
        mv[1][co] += v1*w0 + v2*w1 + v3*w2;
        mv[2][co] += v2*w0 + v3*w1 + v4*w2;
      }
    }
    #pragma unroll
    for (int o = 0; o < 20; o++) acc[o] = 0.f;
    #pragma unroll
    for (int i = 0; i < 3; i++){
      int tt = t0 + i;
      #pragma unroll
      for (int co = 0; co < 3; co++){
        float z = lrelu(mv[i][co]*TBL[86+co] + TBL[89+co]);
        const float* wr = WSr + co*48 + tt;
        #pragma unroll
        for (int o = 0; o < 20; o++)
          acc[o] += z * wr[o*144];
      }
    }
    #pragma unroll
    for (int o = 0; o < 20; o++) acc[o] = rsum16(acc[o]);
    #pragma unroll
    for (int o = 0; o < 20; o++)
      if (seg == (o & 15)) xr[o] = lrelu(acc[o]*TBL[o] + TBL[43+o]);
  }

  // ================= M path ========
  {
    float mv[2][3];
    #pragma unroll
    for (int i = 0; i < 2; i++)
      #pragma unroll
      for (int co = 0; co < 3; co++) mv[i][co] = 0.f;
    int t0 = seg*2;
    #pragma unroll
    for (int ci = 0; ci < 3; ci++){
      int ab = rb + ci*204 + t0;
      float vc = OL[ab];
      #pragma unroll
      for (int k = 0; k < 21; k++){
        float vn = OL[ab + k + 1];
        #pragma unroll
        for (int co = 0; co < 3; co++){
          float wk = mc1w[co*63 + ci*21 + k];
          mv[0][co] += vc*wk;
          mv[1][co] += vn*wk;
        }
        vc = vn;
      }
    }
    #pragma unroll
    for (int o = 0; o < 20; o++) acc[o] = 0.f;
    if (seg < 15){
      #pragma unroll
      for (int co = 0; co < 3; co++){
        float z0 = lrelu(mv[0][co]*TBL[92+co] + TBL[95+co]);
        float z1 = lrelu(mv[1][co]*TBL[92+co] + TBL[95+co]);
        const float* wr = WMr + co*30 + t0;
        #pragma unroll
        for (int o = 0; o < 20; o++){
          float2 q = *(const float2*)(wr + o*90);
          acc[o] += z0*q.x + z1*q.y;
        }
      }
    }
    #pragma unroll
    for (int o = 0; o < 20; o++) acc[o] = rsum16(acc[o]);
    #pragma unroll
    for (int o = 0; o < 20; o++)
      if (seg == (o & 15)) xr[20+o] = lrelu(acc[o]*TBL[20+o] + TBL[63+o]);
  }

  // ================= L path ============================
  {
    float m0 = -3e38f, m1 = -3e38f, m2 = -3e38f;
    int l0 = seg*4;
    int ln = 50 - l0; if (ln > 4) ln = 4;
    for (int j = 0; j < ln; j++){
      m0 = fmaxf(m0, OL[rb +       l0 + j]);
      m1 = fmaxf(m1, OL[rb + 204 + l0 + j]);
      m2 = fmaxf(m2, OL[rb + 408 + l0 + j]);
    }
    m0 = rmax16(m0); m1 = rmax16(m1); m2 = rmax16(m2);
    if (seg == 0) xr[40] = lrelu(m0);
    if (seg == 1) xr[41] = lrelu(m1);
    if (seg == 2) xr[42] = lrelu(m2);
  }
}

// ============ graph21: graph20 + LOCAL CSR. Block n scans the 64KB dst
// array itself (16 edges/thread, L2-broadcast-hot, ~32 matches/block) into
// LDS bucket lists, overlapped with own-node feature loads. Removes: the
// cntg memset stream op, tempo's CSR duty, the cntg->esp global chase. ======
__global__ __launch_bounds__(1024) void k_graph21(
    const float* __restrict__ xbuf,
    const int* __restrict__ ei, const int* __restrict__ et,
    fp gwroot, fp gwrel, fp gb, fp gbnp,
    fp action, fp acw, fp acb,
    float* __restrict__ o_ws)
{
  __shared__ float xin[64][219];       // rows = batches
  __shared__ float lred[16][64];
  __shared__ int cnt[4];
  __shared__ int lst[4][PAD_E];
  int n = blockIdx.x;                  // node 0..499
  int tid = threadIdx.x;
  int w = tid >> 6, lane = tid & 63;
  int b0 = w * 4;                      // this wave's 4 batches

  const float* xb0 = xbuf + (size_t)((b0+0)*NN) * XSTRIDE;
  const float* xb1 = xbuf + (size_t)((b0+1)*NN) * XSTRIDE;
  const float* xb2 = xbuf + (size_t)((b0+2)*NN) * XSTRIDE;
  const float* xb3 = xbuf + (size_t)((b0+3)*NN) * XSTRIDE;

  if (tid < 4) cnt[tid] = 0;
  __syncthreads();

  // ---- local CSR scan (dst array is block-uniform, L2-hot)
  for (int e = tid; e < E_N; e += 1024){
    int d = ei[E_N + e];
    if (d == n){
      int r = et[e];
      int pos = atomicAdd(&cnt[r], 1);
      if (pos < PAD_E) lst[r][pos] = ei[e];
    }
  }

  // ---- own-node features for the 4 batches (overlaps scan)
  if (lane < FF){
    xin[b0+0][lane] = xb0[(size_t)n*XSTRIDE + lane];
    xin[b0+1][lane] = xb1[(size_t)n*XSTRIDE + lane];
    xin[b0+2][lane] = xb2[(size_t)n*XSTRIDE + lane];
    xin[b0+3][lane] = xb3[(size_t)n*XSTRIDE + lane];
  }
  __syncthreads();

  #pragma unroll
  for (int r = 0; r < 4; r++){
    int c = cnt[r];
    if (c > PAD_E) c = PAD_E;
    float a0 = 0.f, a1 = 0.f, a2 = 0.f, a3 = 0.f;
    int i = 0;
    for (; i + 4 <= c; i += 4){
      int s0 = lst[r][i], s1 = lst[r][i+1], s2 = lst[r][i+2], s3 = lst[r][i+3];
      size_t o0 = (size_t)s0*XSTRIDE + lane, o1 = (size_t)s1*XSTRIDE + lane;
      size_t o2 = (size_t)s2*XSTRIDE + lane, o3 = (size_t)s3*XSTRIDE + lane;
      if (lane < FF){
        a0 += xb0[o0] + xb0[o1] + xb0[o2] + xb0[o3];
        a1 += xb1[o0] + xb1[o1] + xb1[o2] + xb1[o3];
        a2 += xb2[o0] + xb2[o1] + xb2[o2] + xb2[o3];
        a3 += xb3[o0] + xb3[o1] + xb3[o2] + xb3[o3];
      }
    }
    for (; i < c; i++){
      int s = lst[r][i];
      size_t o = (size_t)s*XSTRIDE + lane;
      if (lane < FF){
        a0 += xb0[o]; a1 += xb1[o]; a2 += xb2[o]; a3 += xb3[o];
      }
    }
    float inv = 1.f / fmaxf((float)c, 1.f);
    if (lane < FF){
      xin[b0+0][43 + 43*r + lane] = a0 * inv;
      xin[b0+1][43 + 43*r + lane] = a1 * inv;
      xin[b0+2][43 + 43*r + lane] = a2 * inv;
      xin[b0+3][43 + 43*r + lane] = a3 * inv;
    }
  }
  __syncthreads();

  // ---- transform + fused logits: lane = batch, channels split over waves
  int c0 = __builtin_amdgcn_readfirstlane(w * 3);
  float acc[3];
  #pragma unroll
  for (int j = 0; j < 3; j++) acc[j] = (c0 + j < FF) ? gb[c0+j] : 0.f;
  for (int f = 0; f < 43; f++){
    float v = xin[lane][f];
    const float* wp = gwroot + f*43 + c0;
    #pragma unroll
    for (int j = 0; j < 3; j++) acc[j] += v * wp[j];
  }
  for (int f = 0; f < 172; f++){
    float v = xin[lane][43 + f];
    const float* wp = gwrel + f*43 + c0;
    #pragma unroll
    for (int j = 0; j < 3; j++) acc[j] += v * wp[j];
  }
  float lp = 0.f;
  #pragma unroll
  for (int j = 0; j < 3; j++){
    int c = c0 + j;
    if (c < FF){
      float gv = lrelu(bnap(acc[j], gbnp, c, FF));
      lp += gv * acw[1 + FF + c];
    }
  }
  if (w == 15){          // idle in channel space: x/action part (lane = batch)
    float xp = acb[0] + action[lane*(PP+1) + 1 + n] * acw[0];
    #pragma unroll 2
    for (int c = 0; c < FF; c++) xp += xin[lane][c] * acw[1 + c];
    lp = xp;
  }
  lred[w][lane] = lp;
  __syncthreads();
  if (tid < 64){
    float t = 0.f;
    #pragma unroll
    for (int w2 = 0; w2 < 16; w2++) t += lred[w2][tid];
    o_ws[tid*(PP+1) + 1 + n] = t;
  }
}

// ============ fcall2 (unchanged) ============
__global__ __launch_bounds__(512) void k_fcall2(
    const float* __restrict__ o_ws,
    fp aw1, fp ab1, fp aw2, fp ab2, fp aw3, fp ab3,
    float* __restrict__ out)
{
  int b = blockIdx.x;
  int tid = threadIdx.x;
  __shared__ float os[PP+1];
  __shared__ float part[4][HH];
  __shared__ float h1[HH];
  __shared__ float h2[HH];
  __shared__ float red[512];

  if (tid <= PP) os[tid] = (tid == 0) ? 0.f : o_ws[b*(PP+1) + tid];
  __syncthreads();

  {
    int chunk = tid >> 7, h = tid & 127;
    int k0 = chunk * 125;
    int kn = (chunk == 3) ? 126 : 125;
    float acc = 0.f;
    for (int k = 0; k < kn; k++) acc += os[k0+k] * aw1[(k0+k)*HH + h];
    part[chunk][h] = acc;
  }
  __syncthreads();
  if (tid < HH)
    h1[tid] = fmaxf(ab1[tid] + part[0][tid] + part[1][tid] + part[2][tid] + part[3][tid], 0.f);
  __syncthreads();
  if (tid < HH){
    float acc = ab2[tid];
    #pragma unroll 4
    for (int k = 0; k < HH; k++) acc += h1[k] * aw2[k*HH + tid];
    h2[tid] = fmaxf(acc, 0.f);
  }
  __syncthreads();

  float val = -1e30f;
  if (tid <= PP){
    float acc = ab3[tid];
    #pragma unroll 4
    for (int k = 0; k < HH; k++) acc += h2[k] * aw3[k*(PP+1) + tid];
    val = acc;
  }
  red[tid] = val;
  __syncthreads();
  for (int s = 256; s > 0; s >>= 1){
    if (tid < s) red[tid] = fmaxf(red[tid], red[tid + s]);
    __syncthreads();
  }
  float mxv = red[0];
  __syncthreads();
  float e = (tid <= PP) ? expf(val - mxv) : 0.f;
  red[tid] = e;
  __syncthreads();
  for (int s = 256; s > 0; s >>= 1){
    if (tid < s) red[tid] += red[tid + s];
    __syncthreads();
  }
  float sum = red[0];
  if (tid <= PP) out[b*(PP+1) + tid] = e / sum;
}

extern "C" void kernel_launch(void* const* d_in, const int* in_sizes, int n_in,
                              void* d_out, int out_size, void* d_ws, size_t ws_size,
                              hipStream_t stream)
{
  fp obs    = (fp)d_in[0];
  fp action = (fp)d_in[1];
  const int* ei  = (const int*)d_in[2];
  const int* et  = (const int*)d_in[3];
  fp sc1w=(fp)d_in[5],  sc1b=(fp)d_in[6],  sbn1=(fp)d_in[7];
  fp sc2w=(fp)d_in[8],  sc2b=(fp)d_in[9],  sbn2=(fp)d_in[10];
  fp mc1w=(fp)d_in[11], mc1b=(fp)d_in[12], mbn1=(fp)d_in[13];
  fp mc2w=(fp)d_in[14], mc2b=(fp)d_in[15], mbn2=(fp)d_in[16];
  fp gwroot=(fp)d_in[17], gwrel=(fp)d_in[18], gb=(fp)d_in[19], gbnp=(fp)d_in[20];
  fp acw=(fp)d_in[21], acb=(fp)d_in[22];
  fp aw1=(fp)d_in[23], ab1=(fp)d_in[24];
  fp aw2=(fp)d_in[25], ab2=(fp)d_in[26];
  fp aw3=(fp)d_in[27], ab3=(fp)d_in[28];

  float* xbuf   = (float*)d_ws;              // 1,536,000
  float* o_ws   = xbuf + 1536000;            // 32,064

  float* out = (float*)d_out;

  hipLaunchKernelGGL(k_tempo26, dim3(1000), dim3(512), 0, stream,
    obs, sc1w, mc1w, sc2w, mc2w,
    sc1b, sbn1, sc2b, sbn2, mc1b, mbn1, mc2b, mbn2,
    xbuf);
  hipLaunchKernelGGL(k_graph21, dim3(500), dim3(1024), 0, stream,
    xbuf, ei, et, gwroot, gwrel, gb, gbnp, action, acw, acb, o_ws);
  hipLaunchKernelGGL(k_fcall2, dim3(BB), dim3(512), 0, stream,
    o_ws, aw1, ab1, aw2, ab2, aw3, ab3, out);
}

// Round 15
// 214.753 us; speedup vs baseline: 1.1045x; 1.0040x over previous
//
#include <hip/hip_runtime.h>

#define SLOPE 0.01f
#define EPSV  1e-5f
#define BB    64
#define NN    500
#define TT    50
#define E_N   16000
#define FF    43
#define PP    500
#define HH    128
#define XSTRIDE 48
#define PAD_E 40

typedef const float* fp;

__device__ __forceinline__ float lrelu(float x){ return x >= 0.f ? x : SLOPE * x; }
__device__ __forceinline__ float bnap(float x, fp bnp, int c, int C){
  float g  = bnp[c], b_ = bnp[C + c];
  float m  = bnp[2*C + c], v = bnp[3*C + c];
  float s = g * rsqrtf(v + EPSV);
  return x * s + (b_ - m * s);
}

// DPP-based 16-lane (one node = one DPP row) reductions.
#define DPP_I(x, c) __builtin_amdgcn_update_dpp(0, (x), (c), 0xF, 0xF, true)
__device__ __forceinline__ float rsum16(float x){
  x += __int_as_float(DPP_I(__float_as_int(x), 0xB1));   // quad_perm [1,0,3,2]
  x += __int_as_float(DPP_I(__float_as_int(x), 0x4E));   // quad_perm [2,3,0,1]
  x += __int_as_float(DPP_I(__float_as_int(x), 0x124));  // row_ror:4
  x += __int_as_float(DPP_I(__float_as_int(x), 0x128));  // row_ror:8
  return x;
}
__device__ __forceinline__ float rmax16(float x){
  x = fmaxf(x, __int_as_float(DPP_I(__float_as_int(x), 0xB1)));
  x = fmaxf(x, __int_as_float(DPP_I(__float_as_int(x), 0x4E)));
  x = fmaxf(x, __int_as_float(DPP_I(__float_as_int(x), 0x124)));
  x = fmaxf(x, __int_as_float(DPP_I(__float_as_int(x), 0x128)));
  return x;
}

// ============ tempo27: tempo26 + TRANSPOSED conv2 weight staging.
// WSt[(ci*48+tt)*20+o] / WMt[(ci*30+tt)*20+o]: conv2 reads become five
// 16B-aligned ds_read_b128 per (i,co) row (S: 45 b128, M: 30 b128 vs
// 180 b32 + 60 b64 = -40% LDS-pipe cycles). Read banks: S stride 60w ->
// 8 quad-aligned starts tile 32 banks 2-way (free); M stride 40w -> 4
// broadcast addrs (free). Staging write is stride-20 (8-way conflict) but
// one-time: ~73 wave-instr/block, ~2us amortized. ====
__global__ __launch_bounds__(512) void k_tempo27(
    fp obs, fp sc1w, fp mc1w, fp sc2w, fp mc2w,
    fp sc1b, fp sbn1, fp sc2b, fp sbn2,
    fp mc1b, fp mbn1, fp mc2b, fp mbn2,
    float* __restrict__ xbuf)
{
  __shared__ float OL[4896];          // [w][612], 8 waves
  __shared__ float WSt[2880];         // transposed sc2w [(ci*48+tt)*20 + o]
  __shared__ float WMt[1800];         // transposed mc2w [(ci*30+tt)*20 + o]
  __shared__ float TBL[100];
  int tid  = threadIdx.x;
  int w    = tid >> 6, lane = tid & 63;
  int node = lane >> 4, seg = lane & 15;
  int gg   = __builtin_amdgcn_readfirstlane(blockIdx.x*8 + w);   // 0..7999
  int b    = gg / 125, ng = gg - b*125;
  int n0   = ng * 4;
  int wbase = w * 612;

  // ---- transposed weight staging: coalesced global read, strided LDS write
  for (int i = tid; i < 2880; i += 512) WSt[(i%144)*20 + i/144] = sc2w[i];
  for (int i = tid; i < 1800; i += 512) WMt[(i%90)*20 + i/90]  = mc2w[i];

  // ---- bn fold table
  if (tid < 20){
    float g = sbn2[tid], b_ = sbn2[20+tid], m = sbn2[40+tid], v = sbn2[60+tid];
    float s = g * rsqrtf(v + EPSV);
    TBL[tid] = s; TBL[43+tid] = sc2b[tid]*s + (b_ - m*s);
  } else if (tid < 40){
    int o = tid - 20;
    float g = mbn2[o], b_ = mbn2[20+o], m = mbn2[40+o], v = mbn2[60+o];
    float s = g * rsqrtf(v + EPSV);
    TBL[tid] = s; TBL[43+tid] = mc2b[o]*s + (b_ - m*s);
  } else if (tid < 43){
    TBL[tid] = 1.f; TBL[43+tid] = 0.f;
  } else if (tid < 46){
    int ci = tid - 43;
    float g = sbn1[ci], b_ = sbn1[3+ci], m = sbn1[6+ci], v = sbn1[9+ci];
    float s = g * rsqrtf(v + EPSV);
    TBL[86+ci] = s; TBL[89+ci] = sc1b[ci]*s + (b_ - m*s);
  } else if (tid < 49){
    int ci = tid - 46;
    float g = mbn1[ci], b_ = mbn1[3+ci], m = mbn1[6+ci], v = mbn1[9+ci];
    float s = g * rsqrtf(v + EPSV);
    TBL[92+ci] = s; TBL[95+ci] = mc1b[ci]*s + (b_ - m*s);
  }

  // ---- obs staging: 3 channels x 200 contiguous floats per wave (float4)
  for (int c = 0; c < 3; c++){
    if (lane < 50){
      const float4 v = *(const float4*)(obs + ((size_t)(b*3+c)*NN + n0)*TT + lane*4);
      int f = lane*4;
      int n = f/50, t = f - n*50;
      int a = wbase + c*204 + n*51 + t;
      OL[a] = v.x;
      if (++t == 50){ t = 0; n++; a = wbase + c*204 + n*51; } else a++;
      OL[a] = v.y;
      if (++t == 50){ t = 0; n++; a = wbase + c*204 + n*51; } else a++;
      OL[a] = v.z;
      if (++t == 50){ t = 0; n++; a = wbase + c*204 + n*51; } else a++;
      OL[a] = v.w;
    }
  }
  __syncthreads();

  int rb = wbase + node*51;
  int g  = b*NN + n0 + node;
  float* xr = xbuf + (size_t)g * XSTRIDE;
  float acc[20];

  // ================= S path: conv(3-tap) -> bn/lrelu -> conv2(48) =========
  {
    float mv[3][3];                       // [i][co], tt = seg*3 + i
    #pragma unroll
    for (int i = 0; i < 3; i++)
      #pragma unroll
      for (int co = 0; co < 3; co++) mv[i][co] = 0.f;
    int t0 = seg*3;                       // 0..45, window reads t0..t0+4 <= 49
    #pragma unroll
    for (int ci = 0; ci < 3; ci++){
      int ab = rb + ci*204 + t0;
      float v0 = OL[ab], v1 = OL[ab+1], v2 = OL[ab+2], v3 = OL[ab+3], v4 = OL[ab+4];
      #pragma unroll
      for (int co = 0; co < 3; co++){
        float w0 = sc1w[co*9+ci*3+0], w1 = sc1w[co*9+ci*3+1], w2 = sc1w[co*9+ci*3+2];
        mv[0][co] += v0*w0 + v1*w1 + v2*w2;
        mv[1][co] += v1*w0 + v2*w1 + v3*w2;
        mv[2][co] += v2*w0 + v3*w1 + v4*w2;
      }
    }
    #pragma unroll
    for (int o = 0; o < 20; o++) acc[o] = 0.f;
    #pragma unroll
    for (int i = 0; i < 3; i++){
      int tt = t0 + i;                    // 0..47
      #pragma unroll
      for (int co = 0; co < 3; co++){
        float z = lrelu(mv[i][co]*TBL[86+co] + TBL[89+co]);
        const float* wr = WSt + (co*48+tt)*20;
        #pragma unroll
        for (int o = 0; o < 20; o += 4){
          float4 q = *(const float4*)(wr + o);
          acc[o]+=z*q.x; acc[o+1]+=z*q.y; acc[o+2]+=z*q.z; acc[o+3]+=z*q.w;
        }
      }
    }
    #pragma unroll
    for (int o = 0; o < 20; o++) acc[o] = rsum16(acc[o]);
    #pragma unroll
    for (int o = 0; o < 20; o++)
      if (seg == (o & 15)) xr[o] = lrelu(acc[o]*TBL[o] + TBL[43+o]);
  }

  // ================= M path: conv(21-tap) -> bn/lrelu -> conv2(30) ========
  {
    float mv[2][3];                       // tt = seg*2 + i
    #pragma unroll
    for (int i = 0; i < 2; i++)
      #pragma unroll
      for (int co = 0; co < 3; co++) mv[i][co] = 0.f;
    int t0 = seg*2;                       // reads t0..t0+21 (seg15 overreads pad: masked)
    #pragma unroll
    for (int ci = 0; ci < 3; ci++){
      int ab = rb + ci*204 + t0;
      float vc = OL[ab];
      #pragma unroll
      for (int k = 0; k < 21; k++){
        float vn = OL[ab + k + 1];
        #pragma unroll
        for (int co = 0; co < 3; co++){
          float wk = mc1w[co*63 + ci*21 + k];
          mv[0][co] += vc*wk;
          mv[1][co] += vn*wk;
        }
        vc = vn;
      }
    }
    #pragma unroll
    for (int o = 0; o < 20; o++) acc[o] = 0.f;
    if (seg < 15){                        // tt = seg*2, seg*2+1 both < 30
      #pragma unroll
      for (int co = 0; co < 3; co++){
        float z0 = lrelu(mv[0][co]*TBL[92+co] + TBL[95+co]);
        float z1 = lrelu(mv[1][co]*TBL[92+co] + TBL[95+co]);
        const float* wr0 = WMt + (co*30+t0)*20;
        const float* wr1 = wr0 + 20;
        #pragma unroll
        for (int o = 0; o < 20; o += 4){
          float4 q0 = *(const float4*)(wr0 + o);
          float4 q1 = *(const float4*)(wr1 + o);
          acc[o]  += z0*q0.x + z1*q1.x;
          acc[o+1]+= z0*q0.y + z1*q1.y;
          acc[o+2]+= z0*q0.z + z1*q1.z;
          acc[o+3]+= z0*q0.w + z1*q1.w;
        }
      }
    }
    #pragma unroll
    for (int o = 0; o < 20; o++) acc[o] = rsum16(acc[o]);
    #pragma unroll
    for (int o = 0; o < 20; o++)
      if (seg == (o & 15)) xr[20+o] = lrelu(acc[o]*TBL[20+o] + TBL[63+o]);
  }

  // ================= L path: max over t, lrelu ============================
  {
    float m0 = -3e38f, m1 = -3e38f, m2 = -3e38f;
    int l0 = seg*4;
    int ln = 50 - l0; if (ln > 4) ln = 4;  // segs 13..15: ln<=0 -> skip
    for (int j = 0; j < ln; j++){
      m0 = fmaxf(m0, OL[rb +       l0 + j]);
      m1 = fmaxf(m1, OL[rb + 204 + l0 + j]);
      m2 = fmaxf(m2, OL[rb + 408 + l0 + j]);
    }
    m0 = rmax16(m0); m1 = rmax16(m1); m2 = rmax16(m2);
    if (seg == 0) xr[40] = lrelu(m0);
    if (seg == 1) xr[41] = lrelu(m1);
    if (seg == 2) xr[42] = lrelu(m2);
  }
}

// ============ graph21 (unchanged from r14) ======
__global__ __launch_bounds__(1024) void k_graph21(
    const float* __restrict__ xbuf,
    const int* __restrict__ ei, const int* __restrict__ et,
    fp gwroot, fp gwrel, fp gb, fp gbnp,
    fp action, fp acw, fp acb,
    float* __restrict__ o_ws)
{
  __shared__ float xin[64][219];       // rows = batches
  __shared__ float lred[16][64];
  __shared__ int cnt[4];
  __shared__ int lst[4][PAD_E];
  int n = blockIdx.x;                  // node 0..499
  int tid = threadIdx.x;
  int w = tid >> 6, lane = tid & 63;
  int b0 = w * 4;                      // this wave's 4 batches

  const float* xb0 = xbuf + (size_t)((b0+0)*NN) * XSTRIDE;
  const float* xb1 = xbuf + (size_t)((b0+1)*NN) * XSTRIDE;
  const float* xb2 = xbuf + (size_t)((b0+2)*NN) * XSTRIDE;
  const float* xb3 = xbuf + (size_t)((b0+3)*NN) * XSTRIDE;

  if (tid < 4) cnt[tid] = 0;
  __syncthreads();

  // ---- local CSR scan (dst array is block-uniform, L2-hot)
  for (int e = tid; e < E_N; e += 1024){
    int d = ei[E_N + e];
    if (d == n){
      int r = et[e];
      int pos = atomicAdd(&cnt[r], 1);
      if (pos < PAD_E) lst[r][pos] = ei[e];
    }
  }

  // ---- own-node features for the 4 batches (overlaps scan)
  if (lane < FF){
    xin[b0+0][lane] = xb0[(size_t)n*XSTRIDE + lane];
    xin[b0+1][lane] = xb1[(size_t)n*XSTRIDE + lane];
    xin[b0+2][lane] = xb2[(size_t)n*XSTRIDE + lane];
    xin[b0+3][lane] = xb3[(size_t)n*XSTRIDE + lane];
  }
  __syncthreads();

  #pragma unroll
  for (int r = 0; r < 4; r++){
    int c = cnt[r];
    if (c > PAD_E) c = PAD_E;
    float a0 = 0.f, a1 = 0.f, a2 = 0.f, a3 = 0.f;
    int i = 0;
    for (; i + 4 <= c; i += 4){
      int s0 = lst[r][i], s1 = lst[r][i+1], s2 = lst[r][i+2], s3 = lst[r][i+3];
      size_t o0 = (size_t)s0*XSTRIDE + lane, o1 = (size_t)s1*XSTRIDE + lane;
      size_t o2 = (size_t)s2*XSTRIDE + lane, o3 = (size_t)s3*XSTRIDE + lane;
      if (lane < FF){
        a0 += xb0[o0] + xb0[o1] + xb0[o2] + xb0[o3];
        a1 += xb1[o0] + xb1[o1] + xb1[o2] + xb1[o3];
        a2 += xb2[o0] + xb2[o1] + xb2[o2] + xb2[o3];
        a3 += xb3[o0] + xb3[o1] + xb3[o2] + xb3[o3];
      }
    }
    for (; i < c; i++){
      int s = lst[r][i];
      size_t o = (size_t)s*XSTRIDE + lane;
      if (lane < FF){
        a0 += xb0[o]; a1 += xb1[o]; a2 += xb2[o]; a3 += xb3[o];
      }
    }
    float inv = 1.f / fmaxf((float)c, 1.f);
    if (lane < FF){
      xin[b0+0][43 + 43*r + lane] = a0 * inv;
      xin[b0+1][43 + 43*r + lane] = a1 * inv;
      xin[b0+2][43 + 43*r + lane] = a2 * inv;
      xin[b0+3][43 + 43*r + lane] = a3 * inv;
    }
  }
  __syncthreads();

  // ---- transform + fused logits: lane = batch, channels split over waves
  int c0 = __builtin_amdgcn_readfirstlane(w * 3);
  float acc[3];
  #pragma unroll
  for (int j = 0; j < 3; j++) acc[j] = (c0 + j < FF) ? gb[c0+j] : 0.f;
  for (int f = 0; f < 43; f++){
    float v = xin[lane][f];
    const float* wp = gwroot + f*43 + c0;
    #pragma unroll
    for (int j = 0; j < 3; j++) acc[j] += v * wp[j];
  }
  for (int f = 0; f < 172; f++){
    float v = xin[lane][43 + f];
    const float* wp = gwrel + f*43 + c0;
    #pragma unroll
    for (int j = 0; j < 3; j++) acc[j] += v * wp[j];
  }
  float lp = 0.f;
  #pragma unroll
  for (int j = 0; j < 3; j++){
    int c = c0 + j;
    if (c < FF){
      float gv = lrelu(bnap(acc[j], gbnp, c, FF));
      lp += gv * acw[1 + FF + c];
    }
  }
  if (w == 15){          // idle in channel space: x/action part (lane = batch)
    float xp = acb[0] + action[lane*(PP+1) + 1 + n] * acw[0];
    #pragma unroll 2
    for (int c = 0; c < FF; c++) xp += xin[lane][c] * acw[1 + c];
    lp = xp;
  }
  lred[w][lane] = lp;
  __syncthreads();
  if (tid < 64){
    float t = 0.f;
    #pragma unroll
    for (int w2 = 0; w2 < 16; w2++) t += lred[w2][tid];
    o_ws[tid*(PP+1) + 1 + n] = t;
  }
}

// ============ fcall2 (unchanged) ============
__global__ __launch_bounds__(512) void k_fcall2(
    const float* __restrict__ o_ws,
    fp aw1, fp ab1, fp aw2, fp ab2, fp aw3, fp ab3,
    float* __restrict__ out)
{
  int b = blockIdx.x;
  int tid = threadIdx.x;
  __shared__ float os[PP+1];
  __shared__ float part[4][HH];
  __shared__ float h1[HH];
  __shared__ float h2[HH];
  __shared__ float red[512];

  if (tid <= PP) os[tid] = (tid == 0) ? 0.f : o_ws[b*(PP+1) + tid];
  __syncthreads();

  {
    int chunk = tid >> 7, h = tid & 127;
    int k0 = chunk * 125;
    int kn = (chunk == 3) ? 126 : 125;
    float acc = 0.f;
    for (int k = 0; k < kn; k++) acc += os[k0+k] * aw1[(k0+k)*HH + h];
    part[chunk][h] = acc;
  }
  __syncthreads();
  if (tid < HH)
    h1[tid] = fmaxf(ab1[tid] + part[0][tid] + part[1][tid] + part[2][tid] + part[3][tid], 0.f);
  __syncthreads();
  if (tid < HH){
    float acc = ab2[tid];
    #pragma unroll 4
    for (int k = 0; k < HH; k++) acc += h1[k] * aw2[k*HH + tid];
    h2[tid] = fmaxf(acc, 0.f);
  }
  __syncthreads();

  float val = -1e30f;
  if (tid <= PP){
    float acc = ab3[tid];
    #pragma unroll 4
    for (int k = 0; k < HH; k++) acc += h2[k] * aw3[k*(PP+1) + tid];
    val = acc;
  }
  red[tid] = val;
  __syncthreads();
  for (int s = 256; s > 0; s >>= 1){
    if (tid < s) red[tid] = fmaxf(red[tid], red[tid + s]);
    __syncthreads();
  }
  float mxv = red[0];
  __syncthreads();
  float e = (tid <= PP) ? expf(val - mxv) : 0.f;
  red[tid] = e;
  __syncthreads();
  for (int s = 256; s > 0; s >>= 1){
    if (tid < s) red[tid] += red[tid + s];
    __syncthreads();
  }
  float sum = red[0];
  if (tid <= PP) out[b*(PP+1) + tid] = e / sum;
}

extern "C" void kernel_launch(void* const* d_in, const int* in_sizes, int n_in,
                              void* d_out, int out_size, void* d_ws, size_t ws_size,
                              hipStream_t stream)
{
  fp obs    = (fp)d_in[0];
  fp action = (fp)d_in[1];
  const int* ei  = (const int*)d_in[2];
  const int* et  = (const int*)d_in[3];
  fp sc1w=(fp)d_in[5],  sc1b=(fp)d_in[6],  sbn1=(fp)d_in[7];
  fp sc2w=(fp)d_in[8],  sc2b=(fp)d_in[9],  sbn2=(fp)d_in[10];
  fp mc1w=(fp)d_in[11], mc1b=(fp)d_in[12], mbn1=(fp)d_in[13];
  fp mc2w=(fp)d_in[14], mc2b=(fp)d_in[15], mbn2=(fp)d_in[16];
  fp gwroot=(fp)d_in[17], gwrel=(fp)d_in[18], gb=(fp)d_in[19], gbnp=(fp)d_in[20];
  fp acw=(fp)d_in[21], acb=(fp)d_in[22];
  fp aw1=(fp)d_in[23], ab1=(fp)d_in[24];
  fp aw2=(fp)d_in[25], ab2=(fp)d_in[26];
  fp aw3=(fp)d_in[27], ab3=(fp)d_in[28];

  float* xbuf   = (float*)d_ws;              // 1,536,000
  float* o_ws   = xbuf + 1536000;            // 32,064

  float* out = (float*)d_out;

  hipLaunchKernelGGL(k_tempo27, dim3(1000), dim3(512), 0, stream,
    obs, sc1w, mc1w, sc2w, mc2w,
    sc1b, sbn1, sc2b, sbn2, mc1b, mbn1, mc2b, mbn2,
    xbuf);
  hipLaunchKernelGGL(k_graph21, dim3(500), dim3(1024), 0, stream,
    xbuf, ei, et, gwroot, gwrel, gb, gbnp, action, acw, acb, o_ws);
  hipLaunchKernelGGL(k_fcall2, dim3(BB), dim3(512), 0, stream,
    o_ws, aw1, ab1, aw2, ab2, aw3, ab3, out);
}